// Round 1
// baseline (381.550 us; speedup 1.0000x reference)
//
#include <hip/hip_runtime.h>

// GCN encoder: 2x (dense transform -> symmetric-normalized neighbor aggregation)
// Graph preprocessing (degrees, CSR-by-dst) rebuilt every call (ws is re-poisoned).
//
// ws layout (~67 MB): cnt[N] | dinv[N] | row_ptr[N+1] | cursor[N] | col[E] |
//                     h[N*128] | h1[N*128] | h2[N*64]

__global__ __launch_bounds__(256) void k_zero(int* __restrict__ p, int n) {
  int i = blockIdx.x * 256 + threadIdx.x;
  if (i < n) p[i] = 0;
}

__global__ __launch_bounds__(256) void k_count(const int* __restrict__ dst,
                                               int* __restrict__ cnt, int E) {
  int e = blockIdx.x * 256 + threadIdx.x;
  if (e < E) atomicAdd(&cnt[dst[e]], 1);
}

// Single-block exclusive scan of cnt -> row_ptr/cursor; also dinv = rsqrt(cnt+1).
__global__ __launch_bounds__(1024) void k_scan(const int* __restrict__ cnt,
                                               int* __restrict__ row_ptr,
                                               int* __restrict__ cursor,
                                               float* __restrict__ dinv, int n) {
  __shared__ int buf[1024];
  int t = threadIdx.x;
  int carry = 0;
  for (int base = 0; base < n; base += 1024) {
    int i = base + t;
    int v = (i < n) ? cnt[i] : 0;
    buf[t] = v;
    __syncthreads();
    for (int off = 1; off < 1024; off <<= 1) {
      int add = (t >= off) ? buf[t - off] : 0;
      __syncthreads();
      buf[t] += add;
      __syncthreads();
    }
    int excl = carry + buf[t] - v;
    if (i < n) {
      row_ptr[i] = excl;
      cursor[i]  = excl;
      dinv[i]    = rsqrtf((float)(v + 1));  // +1 self loop; deg >= 1 always
    }
    carry += buf[1023];
    __syncthreads();
  }
  if (t == 0) row_ptr[n] = carry;
}

__global__ __launch_bounds__(256) void k_fill(const int* __restrict__ src,
                                              const int* __restrict__ dst,
                                              int* __restrict__ cursor,
                                              int* __restrict__ col, int E) {
  int e = blockIdx.x * 256 + threadIdx.x;
  if (e < E) {
    int pos = atomicAdd(&cursor[dst[e]], 1);
    col[pos] = src[e];
  }
}

// C[n,M] = A[n,128] @ W[128,M].  fp32 vector ALU (no fp32 MFMA on CDNA4).
// W + 32-row A tile staged in LDS; 2 rows x (M/16) cols per thread.
template <int M>
__global__ __launch_bounds__(256) void k_gemm(const float* __restrict__ A,
                                              const float* __restrict__ W,
                                              float* __restrict__ C, int n) {
  constexpr int K = 128;
  constexpr int XS = 132;  // padded row stride: breaks 4-way bank aliasing on x reads
  __shared__ float Ws[K * M];
  __shared__ float Xs[32 * XS];
  int t = threadIdx.x;
  for (int i = t; i < K * M / 4; i += 256)
    ((float4*)Ws)[i] = ((const float4*)W)[i];
  int row0 = blockIdx.x * 32;
  for (int i = t; i < 32 * K / 4; i += 256) {
    int r = i >> 5;        // 32 float4 per row
    int kk = i & 31;
    int gr = row0 + r;
    float4 v = make_float4(0.f, 0.f, 0.f, 0.f);
    if (gr < n) v = ((const float4*)(A + (size_t)gr * K))[kk];
    *(float4*)&Xs[r * XS + kk * 4] = v;
  }
  __syncthreads();
  constexpr int CPT = M / 16;  // 8 (M=128) or 4 (M=64)
  int tc = t & 15;
  int tr = t >> 4;
  const float* x0 = &Xs[(tr * 2 + 0) * XS];
  const float* x1 = &Xs[(tr * 2 + 1) * XS];
  float acc0[CPT] = {};
  float acc1[CPT] = {};
#pragma unroll 4
  for (int k = 0; k < K; k++) {
    float a0 = x0[k], a1 = x1[k];
    const float* w = &Ws[k * M + tc * CPT];
#pragma unroll
    for (int j = 0; j < CPT; j++) {
      float wv = w[j];
      acc0[j] = fmaf(a0, wv, acc0[j]);
      acc1[j] = fmaf(a1, wv, acc1[j]);
    }
  }
  int gr0 = row0 + tr * 2;
  if (gr0 < n) {
#pragma unroll
    for (int j = 0; j < CPT; j += 4)
      *(float4*)&C[(size_t)gr0 * M + tc * CPT + j] =
          make_float4(acc0[j], acc0[j + 1], acc0[j + 2], acc0[j + 3]);
  }
  if (gr0 + 1 < n) {
#pragma unroll
    for (int j = 0; j < CPT; j += 4)
      *(float4*)&C[(size_t)(gr0 + 1) * M + tc * CPT + j] =
          make_float4(acc1[j], acc1[j + 1], acc1[j + 2], acc1[j + 3]);
  }
}

// out[v] = dinv[v]*(sum_{e: dst==v} dinv[src_e]*H[src_e] + dinv[v]*H[v]) + bias
// One wave per node; channels across lanes (VPL floats/lane).
template <int C, bool RELU>
__global__ __launch_bounds__(256) void k_agg(const float* __restrict__ H,
                                             const int* __restrict__ row_ptr,
                                             const int* __restrict__ col,
                                             const float* __restrict__ dinv,
                                             const float* __restrict__ bias,
                                             float* __restrict__ out, int n) {
  constexpr int VPL = C / 64;  // 2 (C=128) or 1 (C=64)
  int lane = threadIdx.x & 63;
  int v = blockIdx.x * 4 + (threadIdx.x >> 6);
  if (v >= n) return;
  float dv = dinv[v];
  float acc[VPL];
  {
    const float* p = &H[(size_t)v * C + lane * VPL];
#pragma unroll
    for (int i = 0; i < VPL; i++) acc[i] = dv * p[i];  // self loop (weight dv)
  }
  int beg = row_ptr[v], end = row_ptr[v + 1];
  for (int base = beg; base < end; base += 64) {
    int m = end - base;
    if (m > 64) m = 64;
    int sl = 0;
    float wl = 0.f;
    if (lane < m) {
      sl = col[base + lane];  // coalesced batch-load of edge ids
      wl = dinv[sl];
    }
    int j = 0;
    for (; j + 4 <= m; j += 4) {  // 4-wide: independent row loads overlap
      int s0 = __shfl(sl, j), s1 = __shfl(sl, j + 1);
      int s2 = __shfl(sl, j + 2), s3 = __shfl(sl, j + 3);
      float w0 = __shfl(wl, j), w1 = __shfl(wl, j + 1);
      float w2 = __shfl(wl, j + 2), w3 = __shfl(wl, j + 3);
      const float* p0 = &H[(size_t)s0 * C + lane * VPL];
      const float* p1 = &H[(size_t)s1 * C + lane * VPL];
      const float* p2 = &H[(size_t)s2 * C + lane * VPL];
      const float* p3 = &H[(size_t)s3 * C + lane * VPL];
#pragma unroll
      for (int i = 0; i < VPL; i++) {
        float h0 = p0[i], h1 = p1[i], h2 = p2[i], h3 = p3[i];
        acc[i] = fmaf(w0, h0, fmaf(w1, h1, fmaf(w2, h2, fmaf(w3, h3, acc[i]))));
      }
    }
    for (; j < m; j++) {
      int s = __shfl(sl, j);
      float wv = __shfl(wl, j);
      const float* p = &H[(size_t)s * C + lane * VPL];
#pragma unroll
      for (int i = 0; i < VPL; i++) acc[i] = fmaf(wv, p[i], acc[i]);
    }
  }
  float* po = &out[(size_t)v * C + lane * VPL];
#pragma unroll
  for (int i = 0; i < VPL; i++) {
    float r = fmaf(dv, acc[i], bias[lane * VPL + i]);
    if (RELU) r = fmaxf(r, 0.f);
    po[i] = r;
  }
}

extern "C" void kernel_launch(void* const* d_in, const int* in_sizes, int n_in,
                              void* d_out, int out_size, void* d_ws, size_t ws_size,
                              hipStream_t stream) {
  const float* x  = (const float*)d_in[0];
  const int*   ei = (const int*)d_in[1];
  const float* W1 = (const float*)d_in[2];
  const float* b1 = (const float*)d_in[3];
  const float* W2 = (const float*)d_in[4];
  const float* b2 = (const float*)d_in[5];
  int N = in_sizes[0] / 128;
  int E = in_sizes[1] / 2;
  const int* src = ei;
  const int* dst = ei + E;

  auto al = [](size_t v) { return (v + 255) & ~(size_t)255; };
  char* w = (char*)d_ws;
  int*   cnt     = (int*)w;   w += al((size_t)N * 4);
  float* dinv    = (float*)w; w += al((size_t)N * 4);
  int*   row_ptr = (int*)w;   w += al((size_t)(N + 1) * 4);
  int*   cursor  = (int*)w;   w += al((size_t)N * 4);
  int*   col     = (int*)w;   w += al((size_t)E * 4);
  float* h       = (float*)w; w += al((size_t)N * 128 * 4);
  float* h1      = (float*)w; w += al((size_t)N * 128 * 4);
  float* h2      = (float*)w; w += al((size_t)N * 64 * 4);
  float* out = (float*)d_out;

  k_zero<<<(N + 255) / 256, 256, 0, stream>>>(cnt, N);
  k_count<<<(E + 255) / 256, 256, 0, stream>>>(dst, cnt, E);
  k_scan<<<1, 1024, 0, stream>>>(cnt, row_ptr, cursor, dinv, N);
  k_fill<<<(E + 255) / 256, 256, 0, stream>>>(src, dst, cursor, col, E);
  k_gemm<128><<<(N + 31) / 32, 256, 0, stream>>>(x, W1, h, N);
  k_agg<128, true><<<(N + 3) / 4, 256, 0, stream>>>(h, row_ptr, col, dinv, b1, h1, N);
  k_gemm<64><<<(N + 31) / 32, 256, 0, stream>>>(h1, W2, h2, N);
  k_agg<64, false><<<(N + 3) / 4, 256, 0, stream>>>(h2, row_ptr, col, dinv, b2, out, N);
}

// Round 2
// 296.257 us; speedup vs baseline: 1.2879x; 1.2879x over previous
//
#include <hip/hip_runtime.h>

// GCN encoder: 2x (dense transform -> symmetric-normalized neighbor aggregation)
// Graph preprocessing (degrees, CSR-by-dst) rebuilt every call (ws is re-poisoned).
//
// ws layout: cnt[N] | dinv[N] | row_ptr[N+1] | cursor[N] | excl[N] | bsum[nb] |
//            col[E] | h[N*128] | h1[N*128] | h2[N*64]

__global__ __launch_bounds__(256) void k_zero(int* __restrict__ p, int n) {
  int i = blockIdx.x * 256 + threadIdx.x;
  if (i < n) p[i] = 0;
}

__global__ __launch_bounds__(256) void k_count(const int* __restrict__ dst,
                                               int* __restrict__ cnt, int E) {
  int e = blockIdx.x * 256 + threadIdx.x;
  if (e < E) atomicAdd(&cnt[dst[e]], 1);
}

// Hierarchical scan, phase 1: per-block (256-wide) exclusive scan + block sum.
// R1 post-mortem: single-block k_scan was 93 us at 0.18% occupancy; this
// 3-kernel version keeps all CUs busy.
__global__ __launch_bounds__(256) void k_scan1(const int* __restrict__ cnt,
                                               int* __restrict__ excl,
                                               int* __restrict__ bsum, int n) {
  __shared__ int buf[256];
  int t = threadIdx.x;
  int i = blockIdx.x * 256 + t;
  int v = (i < n) ? cnt[i] : 0;
  buf[t] = v;
  __syncthreads();
#pragma unroll
  for (int off = 1; off < 256; off <<= 1) {
    int add = (t >= off) ? buf[t - off] : 0;
    __syncthreads();
    buf[t] += add;
    __syncthreads();
  }
  if (i < n) excl[i] = buf[t] - v;
  if (t == 255) bsum[blockIdx.x] = buf[255];
}

// Phase 2: single small block scans the block sums (nb <= 256) in place -> exclusive.
__global__ __launch_bounds__(256) void k_scan2(int* __restrict__ bsum, int nb) {
  __shared__ int buf[256];
  int t = threadIdx.x;
  int v = (t < nb) ? bsum[t] : 0;
  buf[t] = v;
  __syncthreads();
#pragma unroll
  for (int off = 1; off < 256; off <<= 1) {
    int add = (t >= off) ? buf[t - off] : 0;
    __syncthreads();
    buf[t] += add;
    __syncthreads();
  }
  if (t < nb) bsum[t] = buf[t] - v;
}

// Phase 3: combine, write row_ptr/cursor, dinv = rsqrt(deg+1). row_ptr[n]=E (sum
// of counts is exactly E, no readback needed).
__global__ __launch_bounds__(256) void k_scan3(const int* __restrict__ cnt,
                                               const int* __restrict__ excl,
                                               const int* __restrict__ bsum,
                                               int* __restrict__ row_ptr,
                                               int* __restrict__ cursor,
                                               float* __restrict__ dinv, int n, int E) {
  int i = blockIdx.x * 256 + threadIdx.x;
  if (i < n) {
    int e = excl[i] + bsum[i >> 8];
    row_ptr[i] = e;
    cursor[i]  = e;
    dinv[i]    = rsqrtf((float)(cnt[i] + 1));  // +1 self loop; deg >= 1 always
  }
  if (i == 0) row_ptr[n] = E;
}

__global__ __launch_bounds__(256) void k_fill(const int* __restrict__ src,
                                              const int* __restrict__ dst,
                                              int* __restrict__ cursor,
                                              int* __restrict__ col, int E) {
  int e = blockIdx.x * 256 + threadIdx.x;
  if (e < E) {
    int pos = atomicAdd(&cursor[dst[e]], 1);
    col[pos] = src[e];
  }
}

// C[n,M] = A[n,128] @ W[128,M].  fp32 vector ALU (no fp32 MFMA on CDNA4).
// W + 32-row A tile staged in LDS; 2 rows x (M/16) cols per thread.
template <int M>
__global__ __launch_bounds__(256) void k_gemm(const float* __restrict__ A,
                                              const float* __restrict__ W,
                                              float* __restrict__ C, int n) {
  constexpr int K = 128;
  constexpr int XS = 132;  // padded row stride: breaks 4-way bank aliasing on x reads
  __shared__ float Ws[K * M];
  __shared__ float Xs[32 * XS];
  int t = threadIdx.x;
  for (int i = t; i < K * M / 4; i += 256)
    ((float4*)Ws)[i] = ((const float4*)W)[i];
  int row0 = blockIdx.x * 32;
  for (int i = t; i < 32 * K / 4; i += 256) {
    int r = i >> 5;        // 32 float4 per row
    int kk = i & 31;
    int gr = row0 + r;
    float4 v = make_float4(0.f, 0.f, 0.f, 0.f);
    if (gr < n) v = ((const float4*)(A + (size_t)gr * K))[kk];
    *(float4*)&Xs[r * XS + kk * 4] = v;
  }
  __syncthreads();
  constexpr int CPT = M / 16;  // 8 (M=128) or 4 (M=64)
  int tc = t & 15;
  int tr = t >> 4;
  const float* x0 = &Xs[(tr * 2 + 0) * XS];
  const float* x1 = &Xs[(tr * 2 + 1) * XS];
  float acc0[CPT] = {};
  float acc1[CPT] = {};
#pragma unroll 4
  for (int k = 0; k < K; k++) {
    float a0 = x0[k], a1 = x1[k];
    const float* w = &Ws[k * M + tc * CPT];
#pragma unroll
    for (int j = 0; j < CPT; j++) {
      float wv = w[j];
      acc0[j] = fmaf(a0, wv, acc0[j]);
      acc1[j] = fmaf(a1, wv, acc1[j]);
    }
  }
  int gr0 = row0 + tr * 2;
  if (gr0 < n) {
#pragma unroll
    for (int j = 0; j < CPT; j += 4)
      *(float4*)&C[(size_t)gr0 * M + tc * CPT + j] =
          make_float4(acc0[j], acc0[j + 1], acc0[j + 2], acc0[j + 3]);
  }
  if (gr0 + 1 < n) {
#pragma unroll
    for (int j = 0; j < CPT; j += 4)
      *(float4*)&C[(size_t)(gr0 + 1) * M + tc * CPT + j] =
          make_float4(acc1[j], acc1[j + 1], acc1[j + 2], acc1[j + 3]);
  }
}

// out[v] = dinv[v]*(sum_{e: dst==v} dinv[src_e]*H[src_e] + dinv[v]*H[v]) + bias
// One wave per node; channels across lanes (VPL floats/lane).
template <int C, bool RELU>
__global__ __launch_bounds__(256) void k_agg(const float* __restrict__ H,
                                             const int* __restrict__ row_ptr,
                                             const int* __restrict__ col,
                                             const float* __restrict__ dinv,
                                             const float* __restrict__ bias,
                                             float* __restrict__ out, int n) {
  constexpr int VPL = C / 64;  // 2 (C=128) or 1 (C=64)
  int lane = threadIdx.x & 63;
  int v = blockIdx.x * 4 + (threadIdx.x >> 6);
  if (v >= n) return;
  float dv = dinv[v];
  float acc[VPL];
  {
    const float* p = &H[(size_t)v * C + lane * VPL];
#pragma unroll
    for (int i = 0; i < VPL; i++) acc[i] = dv * p[i];  // self loop (weight dv)
  }
  int beg = row_ptr[v], end = row_ptr[v + 1];
  for (int base = beg; base < end; base += 64) {
    int m = end - base;
    if (m > 64) m = 64;
    int sl = 0;
    float wl = 0.f;
    if (lane < m) {
      sl = col[base + lane];  // coalesced batch-load of edge ids
      wl = dinv[sl];
    }
    int j = 0;
    for (; j + 4 <= m; j += 4) {  // 4-wide: independent row loads overlap
      int s0 = __shfl(sl, j), s1 = __shfl(sl, j + 1);
      int s2 = __shfl(sl, j + 2), s3 = __shfl(sl, j + 3);
      float w0 = __shfl(wl, j), w1 = __shfl(wl, j + 1);
      float w2 = __shfl(wl, j + 2), w3 = __shfl(wl, j + 3);
      const float* p0 = &H[(size_t)s0 * C + lane * VPL];
      const float* p1 = &H[(size_t)s1 * C + lane * VPL];
      const float* p2 = &H[(size_t)s2 * C + lane * VPL];
      const float* p3 = &H[(size_t)s3 * C + lane * VPL];
#pragma unroll
      for (int i = 0; i < VPL; i++) {
        float h0 = p0[i], h1 = p1[i], h2 = p2[i], h3 = p3[i];
        acc[i] = fmaf(w0, h0, fmaf(w1, h1, fmaf(w2, h2, fmaf(w3, h3, acc[i]))));
      }
    }
    for (; j < m; j++) {
      int s = __shfl(sl, j);
      float wv = __shfl(wl, j);
      const float* p = &H[(size_t)s * C + lane * VPL];
#pragma unroll
      for (int i = 0; i < VPL; i++) acc[i] = fmaf(wv, p[i], acc[i]);
    }
  }
  float* po = &out[(size_t)v * C + lane * VPL];
#pragma unroll
  for (int i = 0; i < VPL; i++) {
    float r = fmaf(dv, acc[i], bias[lane * VPL + i]);
    if (RELU) r = fmaxf(r, 0.f);
    po[i] = r;
  }
}

extern "C" void kernel_launch(void* const* d_in, const int* in_sizes, int n_in,
                              void* d_out, int out_size, void* d_ws, size_t ws_size,
                              hipStream_t stream) {
  const float* x  = (const float*)d_in[0];
  const int*   ei = (const int*)d_in[1];
  const float* W1 = (const float*)d_in[2];
  const float* b1 = (const float*)d_in[3];
  const float* W2 = (const float*)d_in[4];
  const float* b2 = (const float*)d_in[5];
  int N = in_sizes[0] / 128;
  int E = in_sizes[1] / 2;
  const int* src = ei;
  const int* dst = ei + E;
  int nb = (N + 255) / 256;  // 196 for N=50000; must be <= 256 for k_scan2

  auto al = [](size_t v) { return (v + 255) & ~(size_t)255; };
  char* w = (char*)d_ws;
  int*   cnt     = (int*)w;   w += al((size_t)N * 4);
  float* dinv    = (float*)w; w += al((size_t)N * 4);
  int*   row_ptr = (int*)w;   w += al((size_t)(N + 1) * 4);
  int*   cursor  = (int*)w;   w += al((size_t)N * 4);
  int*   excl    = (int*)w;   w += al((size_t)N * 4);
  int*   bsum    = (int*)w;   w += al((size_t)nb * 4);
  int*   col     = (int*)w;   w += al((size_t)E * 4);
  float* h       = (float*)w; w += al((size_t)N * 128 * 4);
  float* h1      = (float*)w; w += al((size_t)N * 128 * 4);
  float* h2      = (float*)w; w += al((size_t)N * 64 * 4);
  float* out = (float*)d_out;

  k_zero<<<(N + 255) / 256, 256, 0, stream>>>(cnt, N);
  k_count<<<(E + 255) / 256, 256, 0, stream>>>(dst, cnt, E);
  k_scan1<<<nb, 256, 0, stream>>>(cnt, excl, bsum, N);
  k_scan2<<<1, 256, 0, stream>>>(bsum, nb);
  k_scan3<<<nb, 256, 0, stream>>>(cnt, excl, bsum, row_ptr, cursor, dinv, N, E);
  k_fill<<<(E + 255) / 256, 256, 0, stream>>>(src, dst, cursor, col, E);
  k_gemm<128><<<(N + 31) / 32, 256, 0, stream>>>(x, W1, h, N);
  k_agg<128, true><<<(N + 3) / 4, 256, 0, stream>>>(h, row_ptr, col, dinv, b1, h1, N);
  k_gemm<64><<<(N + 31) / 32, 256, 0, stream>>>(h1, W2, h2, N);
  k_agg<64, false><<<(N + 3) / 4, 256, 0, stream>>>(h2, row_ptr, col, dinv, b2, out, N);
}

// Round 3
// 248.283 us; speedup vs baseline: 1.5368x; 1.1932x over previous
//
#include <hip/hip_runtime.h>

// GCN encoder: 2x (dense transform -> symmetric-normalized neighbor aggregation)
// R3: GEMMs moved to bf16x3 split-precision MFMA (no fp32 MFMA on CDNA4; plain
// bf16 would risk the accuracy threshold). A = Ahi+Alo, W = Whi+Wlo (bf16);
// C = Ahi*Whi + Alo*Whi + Ahi*Wlo -> ~1e-4 rel error, matrix-pipe speed.
// No LDS in the GEMM (R2 post-mortem: 80KB LDS -> 1 block/CU -> 9% occupancy,
// plus 6.4M bank conflicts). W is pre-swizzled into B-fragment order so all
// fragment loads are coalesced 16B/lane global loads.

typedef __attribute__((ext_vector_type(8))) short short8;
typedef __attribute__((ext_vector_type(4))) float float4v;

static __device__ __forceinline__ ushort f2bf(float f) {
  union { float f; unsigned u; } c; c.f = f;
  unsigned u = c.u;
  return (ushort)((u + 0x7fffu + ((u >> 16) & 1u)) >> 16);  // RNE
}
static __device__ __forceinline__ float bf2f(ushort h) {
  union { unsigned u; float f; } c; c.u = ((unsigned)h) << 16;
  return c.f;
}

// ---------------- graph preprocessing (unchanged from R2) ----------------

__global__ __launch_bounds__(256) void k_zero(int* __restrict__ p, int n) {
  int i = blockIdx.x * 256 + threadIdx.x;
  if (i < n) p[i] = 0;
}

__global__ __launch_bounds__(256) void k_count(const int* __restrict__ dst,
                                               int* __restrict__ cnt, int E) {
  int e = blockIdx.x * 256 + threadIdx.x;
  if (e < E) atomicAdd(&cnt[dst[e]], 1);
}

__global__ __launch_bounds__(256) void k_scan1(const int* __restrict__ cnt,
                                               int* __restrict__ excl,
                                               int* __restrict__ bsum, int n) {
  __shared__ int buf[256];
  int t = threadIdx.x;
  int i = blockIdx.x * 256 + t;
  int v = (i < n) ? cnt[i] : 0;
  buf[t] = v;
  __syncthreads();
#pragma unroll
  for (int off = 1; off < 256; off <<= 1) {
    int add = (t >= off) ? buf[t - off] : 0;
    __syncthreads();
    buf[t] += add;
    __syncthreads();
  }
  if (i < n) excl[i] = buf[t] - v;
  if (t == 255) bsum[blockIdx.x] = buf[255];
}

__global__ __launch_bounds__(256) void k_scan2(int* __restrict__ bsum, int nb) {
  __shared__ int buf[256];
  int t = threadIdx.x;
  int v = (t < nb) ? bsum[t] : 0;
  buf[t] = v;
  __syncthreads();
#pragma unroll
  for (int off = 1; off < 256; off <<= 1) {
    int add = (t >= off) ? buf[t - off] : 0;
    __syncthreads();
    buf[t] += add;
    __syncthreads();
  }
  if (t < nb) bsum[t] = buf[t] - v;
}

__global__ __launch_bounds__(256) void k_scan3(const int* __restrict__ cnt,
                                               const int* __restrict__ excl,
                                               const int* __restrict__ bsum,
                                               int* __restrict__ row_ptr,
                                               int* __restrict__ cursor,
                                               float* __restrict__ dinv, int n, int E) {
  int i = blockIdx.x * 256 + threadIdx.x;
  if (i < n) {
    int e = excl[i] + bsum[i >> 8];
    row_ptr[i] = e;
    cursor[i]  = e;
    dinv[i]    = rsqrtf((float)(cnt[i] + 1));  // +1 self loop
  }
  if (i == 0) row_ptr[n] = E;
}

__global__ __launch_bounds__(256) void k_fill(const int* __restrict__ src,
                                              const int* __restrict__ dst,
                                              int* __restrict__ cursor,
                                              int* __restrict__ col, int E) {
  int e = blockIdx.x * 256 + threadIdx.x;
  if (e < E) {
    int pos = atomicAdd(&cursor[dst[e]], 1);
    col[pos] = src[e];
  }
}

// ---------------- W pre-swizzle: fp32 W[128,M] -> bf16 hi/lo fragments ----
// Output layout [ktile][ntile][lane][j]: B-frag for 16x16x32 is
// B[k = (lane>>4)*8 + j][n = lane&15]; GEMM loads 16B/lane fully coalesced.
__global__ __launch_bounds__(64) void k_wswz(const float* __restrict__ W,
                                             ushort* __restrict__ whi,
                                             ushort* __restrict__ wlo, int M) {
  int lane = threadIdx.x;
  int ntiles = M >> 4;
  int kt = blockIdx.x / ntiles, nt = blockIdx.x % ntiles;
  int colg = nt * 16 + (lane & 15);
  int krow = kt * 32 + (lane >> 4) * 8;
  ushort h[8], l[8];
#pragma unroll
  for (int j = 0; j < 8; j++) {
    float v = W[(size_t)(krow + j) * M + colg];
    h[j] = f2bf(v);
    l[j] = f2bf(v - bf2f(h[j]));
  }
  size_t o = ((size_t)blockIdx.x * 64 + lane) * 8;
#pragma unroll
  for (int j = 0; j < 8; j++) { whi[o + j] = h[j]; wlo[o + j] = l[j]; }
}

// ---------------- bf16x3 MFMA GEMM: C[n,M] = A[n,128] @ W[128,M] ----------
// PRESPLIT=false: A is fp32, split to hi/lo in registers.
// PRESPLIT=true:  A given as bf16 hi/lo pair (written by k_agg epilogue).
// Block = 256 thr = 4 waves; wave computes 16 rows x M cols; block = 64 rows.
template <int M, bool PRESPLIT>
__global__ __launch_bounds__(256) void k_gemm_mfma(
    const float* __restrict__ Af32,
    const ushort* __restrict__ Ahi, const ushort* __restrict__ Alo,
    const ushort* __restrict__ Whi, const ushort* __restrict__ Wlo,
    float* __restrict__ C, int n) {
  constexpr int K = 128;
  constexpr int NT = M / 16;
  int lane = threadIdx.x & 63;
  int wv = threadIdx.x >> 6;
  int quad = lane >> 4, lo16 = lane & 15;
  int rowbase = blockIdx.x * 64 + wv * 16;
  int arow = rowbase + lo16;
  bool arow_ok = arow < n;

  float4v acc[NT];
#pragma unroll
  for (int nt = 0; nt < NT; nt++) acc[nt] = (float4v){0.f, 0.f, 0.f, 0.f};

  for (int kt = 0; kt < 4; kt++) {
    short8 ahi, alo;
    if (PRESPLIT) {
      size_t ao = (size_t)arow * K + kt * 32 + quad * 8;
      if (arow_ok) {
        ahi = *(const short8*)(Ahi + ao);
        alo = *(const short8*)(Alo + ao);
      } else {
        ahi = (short8)0; alo = (short8)0;
      }
    } else {
      float av[8];
      if (arow_ok) {
        const float* ap = Af32 + (size_t)arow * K + kt * 32 + quad * 8;
        float4 a0 = *(const float4*)ap;
        float4 a1 = *(const float4*)(ap + 4);
        av[0] = a0.x; av[1] = a0.y; av[2] = a0.z; av[3] = a0.w;
        av[4] = a1.x; av[5] = a1.y; av[6] = a1.z; av[7] = a1.w;
      } else {
#pragma unroll
        for (int j = 0; j < 8; j++) av[j] = 0.f;
      }
#pragma unroll
      for (int j = 0; j < 8; j++) {
        ushort h = f2bf(av[j]);
        ahi[j] = (short)h;
        alo[j] = (short)f2bf(av[j] - bf2f(h));
      }
    }
    const ushort* ph = Whi + ((size_t)(kt * NT) * 64 + lane) * 8;
    const ushort* pl = Wlo + ((size_t)(kt * NT) * 64 + lane) * 8;
#pragma unroll
    for (int nt = 0; nt < NT; nt++) {
      short8 bhi = *(const short8*)(ph + nt * 512);
      short8 blo = *(const short8*)(pl + nt * 512);
      acc[nt] = __builtin_amdgcn_mfma_f32_16x16x32_bf16(ahi, bhi, acc[nt], 0, 0, 0);
      acc[nt] = __builtin_amdgcn_mfma_f32_16x16x32_bf16(alo, bhi, acc[nt], 0, 0, 0);
      acc[nt] = __builtin_amdgcn_mfma_f32_16x16x32_bf16(ahi, blo, acc[nt], 0, 0, 0);
    }
  }
  // D layout (m89-verified): col = lane&15, row = quad*4 + reg
#pragma unroll
  for (int nt = 0; nt < NT; nt++) {
#pragma unroll
    for (int r = 0; r < 4; r++) {
      int row = rowbase + quad * 4 + r;
      if (row < n) C[(size_t)row * M + nt * 16 + lo16] = acc[nt][r];
    }
  }
}

// ---------------- aggregation --------------------------------------------
// out[v] = dinv[v]*(sum_{e: dst==v} dinv[src_e]*H[src_e] + dinv[v]*H[v]) + bias
// SPLIT: write bf16 hi/lo pair (feeds the PRESPLIT GEMM) instead of fp32.
template <int C, bool RELU, bool SPLIT>
__global__ __launch_bounds__(256) void k_agg(const float* __restrict__ H,
                                             const int* __restrict__ row_ptr,
                                             const int* __restrict__ col,
                                             const float* __restrict__ dinv,
                                             const float* __restrict__ bias,
                                             float* __restrict__ out,
                                             ushort* __restrict__ outhi,
                                             ushort* __restrict__ outlo, int n) {
  constexpr int VPL = C / 64;  // 2 (C=128) or 1 (C=64)
  int lane = threadIdx.x & 63;
  int v = blockIdx.x * 4 + (threadIdx.x >> 6);
  if (v >= n) return;
  float dv = dinv[v];
  float acc[VPL];
  {
    const float* p = &H[(size_t)v * C + lane * VPL];
#pragma unroll
    for (int i = 0; i < VPL; i++) acc[i] = dv * p[i];  // self loop (weight dv)
  }
  int beg = row_ptr[v], end = row_ptr[v + 1];
  for (int base = beg; base < end; base += 64) {
    int m = end - base;
    if (m > 64) m = 64;
    int sl = 0;
    float wl = 0.f;
    if (lane < m) {
      sl = col[base + lane];
      wl = dinv[sl];
    }
    int j = 0;
    for (; j + 4 <= m; j += 4) {
      int s0 = __shfl(sl, j), s1 = __shfl(sl, j + 1);
      int s2 = __shfl(sl, j + 2), s3 = __shfl(sl, j + 3);
      float w0 = __shfl(wl, j), w1 = __shfl(wl, j + 1);
      float w2 = __shfl(wl, j + 2), w3 = __shfl(wl, j + 3);
      const float* p0 = &H[(size_t)s0 * C + lane * VPL];
      const float* p1 = &H[(size_t)s1 * C + lane * VPL];
      const float* p2 = &H[(size_t)s2 * C + lane * VPL];
      const float* p3 = &H[(size_t)s3 * C + lane * VPL];
#pragma unroll
      for (int i = 0; i < VPL; i++) {
        float h0 = p0[i], h1 = p1[i], h2 = p2[i], h3 = p3[i];
        acc[i] = fmaf(w0, h0, fmaf(w1, h1, fmaf(w2, h2, fmaf(w3, h3, acc[i]))));
      }
    }
    for (; j < m; j++) {
      int s = __shfl(sl, j);
      float wv = __shfl(wl, j);
      const float* p = &H[(size_t)s * C + lane * VPL];
#pragma unroll
      for (int i = 0; i < VPL; i++) acc[i] = fmaf(wv, p[i], acc[i]);
    }
  }
  float r[VPL];
#pragma unroll
  for (int i = 0; i < VPL; i++) {
    r[i] = fmaf(dv, acc[i], bias[lane * VPL + i]);
    if (RELU) r[i] = fmaxf(r[i], 0.f);
  }
  if (SPLIT) {
    // C==128 path: pack 2 bf16 per lane -> one 4B store each for hi and lo
    unsigned uh = 0, ul = 0;
#pragma unroll
    for (int i = 0; i < VPL; i++) {
      ushort h = f2bf(r[i]);
      ushort l = f2bf(r[i] - bf2f(h));
      uh |= ((unsigned)h) << (16 * i);
      ul |= ((unsigned)l) << (16 * i);
    }
    ((unsigned*)outhi)[(size_t)v * (C / 2) + lane] = uh;
    ((unsigned*)outlo)[(size_t)v * (C / 2) + lane] = ul;
  } else {
    float* po = &out[(size_t)v * C + lane * VPL];
#pragma unroll
    for (int i = 0; i < VPL; i++) po[i] = r[i];
  }
}

extern "C" void kernel_launch(void* const* d_in, const int* in_sizes, int n_in,
                              void* d_out, int out_size, void* d_ws, size_t ws_size,
                              hipStream_t stream) {
  const float* x  = (const float*)d_in[0];
  const int*   ei = (const int*)d_in[1];
  const float* W1 = (const float*)d_in[2];
  const float* b1 = (const float*)d_in[3];
  const float* W2 = (const float*)d_in[4];
  const float* b2 = (const float*)d_in[5];
  int N = in_sizes[0] / 128;
  int E = in_sizes[1] / 2;
  const int* src = ei;
  const int* dst = ei + E;
  int nb = (N + 255) / 256;  // 196 for N=50000; must be <= 256 for k_scan2

  auto al = [](size_t v) { return (v + 255) & ~(size_t)255; };
  char* w = (char*)d_ws;
  int*    cnt     = (int*)w;    w += al((size_t)N * 4);
  float*  dinv    = (float*)w;  w += al((size_t)N * 4);
  int*    row_ptr = (int*)w;    w += al((size_t)(N + 1) * 4);
  int*    cursor  = (int*)w;    w += al((size_t)N * 4);
  int*    excl    = (int*)w;    w += al((size_t)N * 4);
  int*    bsum    = (int*)w;    w += al((size_t)nb * 4);
  int*    colv    = (int*)w;    w += al((size_t)E * 4);
  float*  h       = (float*)w;  w += al((size_t)N * 128 * 4);
  ushort* h1hi    = (ushort*)w; w += al((size_t)N * 128 * 2);
  ushort* h1lo    = (ushort*)w; w += al((size_t)N * 128 * 2);
  float*  h2      = (float*)w;  w += al((size_t)N * 64 * 4);
  ushort* w1hi    = (ushort*)w; w += al((size_t)128 * 128 * 2);
  ushort* w1lo    = (ushort*)w; w += al((size_t)128 * 128 * 2);
  ushort* w2hi    = (ushort*)w; w += al((size_t)128 * 64 * 2);
  ushort* w2lo    = (ushort*)w; w += al((size_t)128 * 64 * 2);
  float* out = (float*)d_out;

  k_zero<<<(N + 255) / 256, 256, 0, stream>>>(cnt, N);
  k_count<<<(E + 255) / 256, 256, 0, stream>>>(dst, cnt, E);
  k_scan1<<<nb, 256, 0, stream>>>(cnt, excl, bsum, N);
  k_scan2<<<1, 256, 0, stream>>>(bsum, nb);
  k_scan3<<<nb, 256, 0, stream>>>(cnt, excl, bsum, row_ptr, cursor, dinv, N, E);
  k_fill<<<(E + 255) / 256, 256, 0, stream>>>(src, dst, cursor, colv, E);
  k_wswz<<<4 * 8, 64, 0, stream>>>(W1, w1hi, w1lo, 128);
  k_wswz<<<4 * 4, 64, 0, stream>>>(W2, w2hi, w2lo, 64);

  int gb = (N + 63) / 64;
  k_gemm_mfma<128, false><<<gb, 256, 0, stream>>>(x, nullptr, nullptr, w1hi, w1lo, h, N);
  k_agg<128, true, true><<<(N + 3) / 4, 256, 0, stream>>>(h, row_ptr, colv, dinv, b1,
                                                          nullptr, h1hi, h1lo, N);
  k_gemm_mfma<64, true><<<gb, 256, 0, stream>>>(nullptr, h1hi, h1lo, w2hi, w2lo, h2, N);
  k_agg<64, false, false><<<(N + 3) / 4, 256, 0, stream>>>(h2, row_ptr, colv, dinv, b2,
                                                           out, nullptr, nullptr, N);
}

// Round 4
// 224.745 us; speedup vs baseline: 1.6977x; 1.1047x over previous
//
#include <hip/hip_runtime.h>

// GCN encoder: 2x (dense transform -> symmetric-normalized neighbor aggregation)
// R3: bf16x3 split MFMA GEMMs (no fp32 MFMA on CDNA4), W pre-swizzled to
//     B-fragment order, no LDS in GEMM.
// R4: aggregation gather tables (h, h2) stored as bf16 -> halves the
//     beyond-L2 gather traffic that bound k_agg (R3: FETCH 145 MB @ 3.0 TB/s,
//     VALUBusy 19% -> pure gather-BW bound). Accumulation stays fp32; h1
//     (GEMM2 input) stays bf16 hi/lo so GEMM precision is preserved.

typedef __attribute__((ext_vector_type(8))) short short8;
typedef __attribute__((ext_vector_type(4))) float float4v;

static __device__ __forceinline__ ushort f2bf(float f) {
  union { float f; unsigned u; } c; c.f = f;
  unsigned u = c.u;
  return (ushort)((u + 0x7fffu + ((u >> 16) & 1u)) >> 16);  // RNE
}
static __device__ __forceinline__ float bf2f(ushort h) {
  union { unsigned u; float f; } c; c.u = ((unsigned)h) << 16;
  return c.f;
}
static __device__ __forceinline__ float bfhi(unsigned packed) {  // elem1 of pair
  union { unsigned u; float f; } c; c.u = packed & 0xffff0000u;
  return c.f;
}
static __device__ __forceinline__ float bflo(unsigned packed) {  // elem0 of pair
  union { unsigned u; float f; } c; c.u = packed << 16;
  return c.f;
}

// ---------------- graph preprocessing (unchanged from R2) ----------------

__global__ __launch_bounds__(256) void k_zero(int* __restrict__ p, int n) {
  int i = blockIdx.x * 256 + threadIdx.x;
  if (i < n) p[i] = 0;
}

__global__ __launch_bounds__(256) void k_count(const int* __restrict__ dst,
                                               int* __restrict__ cnt, int E) {
  int e = blockIdx.x * 256 + threadIdx.x;
  if (e < E) atomicAdd(&cnt[dst[e]], 1);
}

__global__ __launch_bounds__(256) void k_scan1(const int* __restrict__ cnt,
                                               int* __restrict__ excl,
                                               int* __restrict__ bsum, int n) {
  __shared__ int buf[256];
  int t = threadIdx.x;
  int i = blockIdx.x * 256 + t;
  int v = (i < n) ? cnt[i] : 0;
  buf[t] = v;
  __syncthreads();
#pragma unroll
  for (int off = 1; off < 256; off <<= 1) {
    int add = (t >= off) ? buf[t - off] : 0;
    __syncthreads();
    buf[t] += add;
    __syncthreads();
  }
  if (i < n) excl[i] = buf[t] - v;
  if (t == 255) bsum[blockIdx.x] = buf[255];
}

__global__ __launch_bounds__(256) void k_scan2(int* __restrict__ bsum, int nb) {
  __shared__ int buf[256];
  int t = threadIdx.x;
  int v = (t < nb) ? bsum[t] : 0;
  buf[t] = v;
  __syncthreads();
#pragma unroll
  for (int off = 1; off < 256; off <<= 1) {
    int add = (t >= off) ? buf[t - off] : 0;
    __syncthreads();
    buf[t] += add;
    __syncthreads();
  }
  if (t < nb) bsum[t] = buf[t] - v;
}

__global__ __launch_bounds__(256) void k_scan3(const int* __restrict__ cnt,
                                               const int* __restrict__ excl,
                                               const int* __restrict__ bsum,
                                               int* __restrict__ row_ptr,
                                               int* __restrict__ cursor,
                                               float* __restrict__ dinv, int n, int E) {
  int i = blockIdx.x * 256 + threadIdx.x;
  if (i < n) {
    int e = excl[i] + bsum[i >> 8];
    row_ptr[i] = e;
    cursor[i]  = e;
    dinv[i]    = rsqrtf((float)(cnt[i] + 1));  // +1 self loop
  }
  if (i == 0) row_ptr[n] = E;
}

__global__ __launch_bounds__(256) void k_fill(const int* __restrict__ src,
                                              const int* __restrict__ dst,
                                              int* __restrict__ cursor,
                                              int* __restrict__ col, int E) {
  int e = blockIdx.x * 256 + threadIdx.x;
  if (e < E) {
    int pos = atomicAdd(&cursor[dst[e]], 1);
    col[pos] = src[e];
  }
}

// ---------------- W pre-swizzle: fp32 W[128,M] -> bf16 hi/lo fragments ----
// Layout [ktile][ntile][lane][j]: B-frag for 16x16x32: B[k=(lane>>4)*8+j][n=lane&15]
__global__ __launch_bounds__(64) void k_wswz(const float* __restrict__ W,
                                             ushort* __restrict__ whi,
                                             ushort* __restrict__ wlo, int M) {
  int lane = threadIdx.x;
  int ntiles = M >> 4;
  int kt = blockIdx.x / ntiles, nt = blockIdx.x % ntiles;
  int colg = nt * 16 + (lane & 15);
  int krow = kt * 32 + (lane >> 4) * 8;
  ushort h[8], l[8];
#pragma unroll
  for (int j = 0; j < 8; j++) {
    float v = W[(size_t)(krow + j) * M + colg];
    h[j] = f2bf(v);
    l[j] = f2bf(v - bf2f(h[j]));
  }
  size_t o = ((size_t)blockIdx.x * 64 + lane) * 8;
#pragma unroll
  for (int j = 0; j < 8; j++) { whi[o + j] = h[j]; wlo[o + j] = l[j]; }
}

// ---------------- bf16x3 MFMA GEMM: C[n,M] = A[n,128] @ W[128,M] ----------
// Output written as bf16 (feeds the gather-bound aggregation; R4).
template <int M, bool PRESPLIT>
__global__ __launch_bounds__(256) void k_gemm_mfma(
    const float* __restrict__ Af32,
    const ushort* __restrict__ Ahi, const ushort* __restrict__ Alo,
    const ushort* __restrict__ Whi, const ushort* __restrict__ Wlo,
    ushort* __restrict__ Cb, int n) {
  constexpr int K = 128;
  constexpr int NT = M / 16;
  int lane = threadIdx.x & 63;
  int wv = threadIdx.x >> 6;
  int quad = lane >> 4, lo16 = lane & 15;
  int rowbase = blockIdx.x * 64 + wv * 16;
  int arow = rowbase + lo16;
  bool arow_ok = arow < n;

  float4v acc[NT];
#pragma unroll
  for (int nt = 0; nt < NT; nt++) acc[nt] = (float4v){0.f, 0.f, 0.f, 0.f};

  for (int kt = 0; kt < 4; kt++) {
    short8 ahi, alo;
    if (PRESPLIT) {
      size_t ao = (size_t)arow * K + kt * 32 + quad * 8;
      if (arow_ok) {
        ahi = *(const short8*)(Ahi + ao);
        alo = *(const short8*)(Alo + ao);
      } else {
        ahi = (short8)0; alo = (short8)0;
      }
    } else {
      float av[8];
      if (arow_ok) {
        const float* ap = Af32 + (size_t)arow * K + kt * 32 + quad * 8;
        float4 a0 = *(const float4*)ap;
        float4 a1 = *(const float4*)(ap + 4);
        av[0] = a0.x; av[1] = a0.y; av[2] = a0.z; av[3] = a0.w;
        av[4] = a1.x; av[5] = a1.y; av[6] = a1.z; av[7] = a1.w;
      } else {
#pragma unroll
        for (int j = 0; j < 8; j++) av[j] = 0.f;
      }
#pragma unroll
      for (int j = 0; j < 8; j++) {
        ushort h = f2bf(av[j]);
        ahi[j] = (short)h;
        alo[j] = (short)f2bf(av[j] - bf2f(h));
      }
    }
    const ushort* ph = Whi + ((size_t)(kt * NT) * 64 + lane) * 8;
    const ushort* pl = Wlo + ((size_t)(kt * NT) * 64 + lane) * 8;
#pragma unroll
    for (int nt = 0; nt < NT; nt++) {
      short8 bhi = *(const short8*)(ph + nt * 512);
      short8 blo = *(const short8*)(pl + nt * 512);
      acc[nt] = __builtin_amdgcn_mfma_f32_16x16x32_bf16(ahi, bhi, acc[nt], 0, 0, 0);
      acc[nt] = __builtin_amdgcn_mfma_f32_16x16x32_bf16(alo, bhi, acc[nt], 0, 0, 0);
      acc[nt] = __builtin_amdgcn_mfma_f32_16x16x32_bf16(ahi, blo, acc[nt], 0, 0, 0);
    }
  }
  // D layout (m89-verified): col = lane&15, row = quad*4 + reg
#pragma unroll
  for (int nt = 0; nt < NT; nt++) {
#pragma unroll
    for (int r = 0; r < 4; r++) {
      int row = rowbase + quad * 4 + r;
      if (row < n) Cb[(size_t)row * M + nt * 16 + lo16] = f2bf(acc[nt][r]);
    }
  }
}

// ---------------- aggregation --------------------------------------------
// out[v] = dinv[v]*(sum_{e: dst==v} dinv[src_e]*Hb[src_e] + dinv[v]*Hb[v]) + bias
// Hb is bf16 [n,C] (R4: half the gather bytes). Accumulation fp32.
// SPLIT: write bf16 hi/lo pair (feeds PRESPLIT GEMM2); else fp32.
template <int C, bool RELU, bool SPLIT>
__global__ __launch_bounds__(256) void k_agg(const ushort* __restrict__ Hb,
                                             const int* __restrict__ row_ptr,
                                             const int* __restrict__ col,
                                             const float* __restrict__ dinv,
                                             const float* __restrict__ bias,
                                             float* __restrict__ out,
                                             ushort* __restrict__ outhi,
                                             ushort* __restrict__ outlo, int n) {
  constexpr int VPL = C / 64;  // 2 (C=128) or 1 (C=64)
  int lane = threadIdx.x & 63;
  int v = blockIdx.x * 4 + (threadIdx.x >> 6);
  if (v >= n) return;
  float dv = dinv[v];
  float acc0 = 0.f, acc1 = 0.f;

  // packed-row loader: C=128 -> 4B (2 bf16), C=64 -> 2B (1 bf16)
  auto loadp = [&](int s) -> unsigned {
    if (VPL == 2) return *(const unsigned*)(Hb + (size_t)s * C + lane * 2);
    else          return (unsigned)Hb[(size_t)s * C + lane];
  };
  {
    unsigned u = loadp(v);  // self loop (weight dv)
    if (VPL == 2) { acc0 = dv * bflo(u); acc1 = dv * bfhi(u); }
    else          { acc0 = dv * bf2f((ushort)u); }
  }
  int beg = row_ptr[v], end = row_ptr[v + 1];
  for (int base = beg; base < end; base += 64) {
    int m = end - base;
    if (m > 64) m = 64;
    int sl = 0;
    float wl = 0.f;
    if (lane < m) {
      sl = col[base + lane];  // coalesced batch-load of edge ids
      wl = dinv[sl];
    }
    int j = 0;
    for (; j + 8 <= m; j += 8) {  // 8 outstanding half-size gathers (R4)
      int s[8]; float wq[8]; unsigned u[8];
#pragma unroll
      for (int q = 0; q < 8; q++) { s[q] = __shfl(sl, j + q); wq[q] = __shfl(wl, j + q); }
#pragma unroll
      for (int q = 0; q < 8; q++) u[q] = loadp(s[q]);
#pragma unroll
      for (int q = 0; q < 8; q++) {
        if (VPL == 2) {
          acc0 = fmaf(wq[q], bflo(u[q]), acc0);
          acc1 = fmaf(wq[q], bfhi(u[q]), acc1);
        } else {
          acc0 = fmaf(wq[q], bf2f((ushort)u[q]), acc0);
        }
      }
    }
    for (; j + 4 <= m; j += 4) {
      int s[4]; float wq[4]; unsigned u[4];
#pragma unroll
      for (int q = 0; q < 4; q++) { s[q] = __shfl(sl, j + q); wq[q] = __shfl(wl, j + q); }
#pragma unroll
      for (int q = 0; q < 4; q++) u[q] = loadp(s[q]);
#pragma unroll
      for (int q = 0; q < 4; q++) {
        if (VPL == 2) {
          acc0 = fmaf(wq[q], bflo(u[q]), acc0);
          acc1 = fmaf(wq[q], bfhi(u[q]), acc1);
        } else {
          acc0 = fmaf(wq[q], bf2f((ushort)u[q]), acc0);
        }
      }
    }
    for (; j < m; j++) {
      int s = __shfl(sl, j);
      float wv = __shfl(wl, j);
      unsigned u = loadp(s);
      if (VPL == 2) {
        acc0 = fmaf(wv, bflo(u), acc0);
        acc1 = fmaf(wv, bfhi(u), acc1);
      } else {
        acc0 = fmaf(wv, bf2f((ushort)u), acc0);
      }
    }
  }
  float r0 = fmaf(dv, acc0, bias[lane * VPL + 0]);
  if (RELU) r0 = fmaxf(r0, 0.f);
  if (VPL == 2) {
    float r1 = fmaf(dv, acc1, bias[lane * VPL + 1]);
    if (RELU) r1 = fmaxf(r1, 0.f);
    if (SPLIT) {
      ushort h0 = f2bf(r0), h1 = f2bf(r1);
      ushort l0 = f2bf(r0 - bf2f(h0)), l1 = f2bf(r1 - bf2f(h1));
      ((unsigned*)outhi)[(size_t)v * (C / 2) + lane] = (unsigned)h0 | ((unsigned)h1 << 16);
      ((unsigned*)outlo)[(size_t)v * (C / 2) + lane] = (unsigned)l0 | ((unsigned)l1 << 16);
    } else {
      *(float2*)&out[(size_t)v * C + lane * 2] = make_float2(r0, r1);
    }
  } else {
    if (SPLIT) {
      ushort h0 = f2bf(r0);
      outhi[(size_t)v * C + lane] = h0;
      outlo[(size_t)v * C + lane] = f2bf(r0 - bf2f(h0));
    } else {
      out[(size_t)v * C + lane] = r0;
    }
  }
}

extern "C" void kernel_launch(void* const* d_in, const int* in_sizes, int n_in,
                              void* d_out, int out_size, void* d_ws, size_t ws_size,
                              hipStream_t stream) {
  const float* x  = (const float*)d_in[0];
  const int*   ei = (const int*)d_in[1];
  const float* W1 = (const float*)d_in[2];
  const float* b1 = (const float*)d_in[3];
  const float* W2 = (const float*)d_in[4];
  const float* b2 = (const float*)d_in[5];
  int N = in_sizes[0] / 128;
  int E = in_sizes[1] / 2;
  const int* src = ei;
  const int* dst = ei + E;
  int nb = (N + 255) / 256;  // 196 for N=50000; must be <= 256 for k_scan2

  auto al = [](size_t v) { return (v + 255) & ~(size_t)255; };
  char* w = (char*)d_ws;
  int*    cnt     = (int*)w;    w += al((size_t)N * 4);
  float*  dinv    = (float*)w;  w += al((size_t)N * 4);
  int*    row_ptr = (int*)w;    w += al((size_t)(N + 1) * 4);
  int*    cursor  = (int*)w;    w += al((size_t)N * 4);
  int*    excl    = (int*)w;    w += al((size_t)N * 4);
  int*    bsum    = (int*)w;    w += al((size_t)nb * 4);
  int*    colv    = (int*)w;    w += al((size_t)E * 4);
  ushort* h       = (ushort*)w; w += al((size_t)N * 128 * 2);  // bf16 (R4)
  ushort* h1hi    = (ushort*)w; w += al((size_t)N * 128 * 2);
  ushort* h1lo    = (ushort*)w; w += al((size_t)N * 128 * 2);
  ushort* h2      = (ushort*)w; w += al((size_t)N * 64 * 2);   // bf16 (R4)
  ushort* w1hi    = (ushort*)w; w += al((size_t)128 * 128 * 2);
  ushort* w1lo    = (ushort*)w; w += al((size_t)128 * 128 * 2);
  ushort* w2hi    = (ushort*)w; w += al((size_t)128 * 64 * 2);
  ushort* w2lo    = (ushort*)w; w += al((size_t)128 * 64 * 2);
  float* out = (float*)d_out;

  k_zero<<<(N + 255) / 256, 256, 0, stream>>>(cnt, N);
  k_count<<<(E + 255) / 256, 256, 0, stream>>>(dst, cnt, E);
  k_scan1<<<nb, 256, 0, stream>>>(cnt, excl, bsum, N);
  k_scan2<<<1, 256, 0, stream>>>(bsum, nb);
  k_scan3<<<nb, 256, 0, stream>>>(cnt, excl, bsum, row_ptr, cursor, dinv, N, E);
  k_fill<<<(E + 255) / 256, 256, 0, stream>>>(src, dst, cursor, colv, E);
  k_wswz<<<4 * 8, 64, 0, stream>>>(W1, w1hi, w1lo, 128);
  k_wswz<<<4 * 4, 64, 0, stream>>>(W2, w2hi, w2lo, 64);

  int gb = (N + 63) / 64;
  k_gemm_mfma<128, false><<<gb, 256, 0, stream>>>(x, nullptr, nullptr, w1hi, w1lo, h, N);
  k_agg<128, true, true><<<(N + 3) / 4, 256, 0, stream>>>(h, row_ptr, colv, dinv, b1,
                                                          nullptr, h1hi, h1lo, N);
  k_gemm_mfma<64, true><<<gb, 256, 0, stream>>>(nullptr, h1hi, h1lo, w2hi, w2lo, h2, N);
  k_agg<64, false, false><<<(N + 3) / 4, 256, 0, stream>>>(h2, row_ptr, colv, dinv, b2,
                                                           out, nullptr, nullptr, N);
}

// Round 6
// 218.101 us; speedup vs baseline: 1.7494x; 1.0305x over previous
//
#include <hip/hip_runtime.h>

// GCN encoder: 2x (dense transform -> symmetric-normalized neighbor aggregation)
// R3: bf16x3 split MFMA GEMMs (no fp32 MFMA on CDNA4), W pre-swizzled to
//     B-fragment order, no LDS in GEMM.
// R4: aggregation gather tables (h, h2) stored bf16 -> halved beyond-L2 traffic.
// R5 FAILED: ticket-fused scan had a cross-thread fence race (t==255 wrote
//     bsum, t==0 fenced) -> garbage row_ptr -> OOB writes in k_fill -> abort.
// R6: keep the two race-free fusions (k_pre = zero+wswz, k_cg1 = gemm1||count,
//     disjoint work, no inter-block comms) + int4 edge loads; revert scan to
//     the proven 3-kernel hierarchical version. 9 dispatches total.

typedef __attribute__((ext_vector_type(8))) short short8;
typedef __attribute__((ext_vector_type(4))) float float4v;

static __device__ __forceinline__ ushort f2bf(float f) {
  union { float f; unsigned u; } c; c.f = f;
  unsigned u = c.u;
  return (ushort)((u + 0x7fffu + ((u >> 16) & 1u)) >> 16);  // RNE
}
static __device__ __forceinline__ float bf2f(ushort h) {
  union { unsigned u; float f; } c; c.u = ((unsigned)h) << 16;
  return c.f;
}
static __device__ __forceinline__ float bfhi(unsigned packed) {
  union { unsigned u; float f; } c; c.u = packed & 0xffff0000u;
  return c.f;
}
static __device__ __forceinline__ float bflo(unsigned packed) {
  union { unsigned u; float f; } c; c.u = packed << 16;
  return c.f;
}

// W swizzle body: one 16x32 B-fragment tile (64 lanes).
// Layout [ktile][ntile][lane][j]: B[k=(lane>>4)*8+j][n=lane&15]
static __device__ __forceinline__ void wswz_tile(const float* __restrict__ W,
                                                 ushort* __restrict__ whi,
                                                 ushort* __restrict__ wlo,
                                                 int M, int tile, int lane) {
  int ntiles = M >> 4;
  int kt = tile / ntiles, nt = tile % ntiles;
  int colg = nt * 16 + (lane & 15);
  int krow = kt * 32 + (lane >> 4) * 8;
  size_t o = ((size_t)tile * 64 + lane) * 8;
#pragma unroll
  for (int j = 0; j < 8; j++) {
    float v = W[(size_t)(krow + j) * M + colg];
    ushort h = f2bf(v);
    whi[o + j] = h;
    wlo[o + j] = f2bf(v - bf2f(h));
  }
}

// ---------------- k_pre: zero cnt, swizzle W1 and W2 ----------------------
// blocks [0, nzb): zero; blocks [nzb, nzb+12): 4 swizzle tiles each (48 total:
// W1 = tiles 0..31 (M=128), W2 = tiles 32..47 (M=64)).
__global__ __launch_bounds__(256) void k_pre(int* __restrict__ cnt, int n, int nzb,
                                             const float* __restrict__ W1,
                                             ushort* __restrict__ w1hi,
                                             ushort* __restrict__ w1lo,
                                             const float* __restrict__ W2,
                                             ushort* __restrict__ w2hi,
                                             ushort* __restrict__ w2lo) {
  int bid = blockIdx.x, t = threadIdx.x;
  if (bid < nzb) {
    int i = bid * 256 + t;
    if (i < n) cnt[i] = 0;
  } else {
    int tile = (bid - nzb) * 4 + (t >> 6);
    int lane = t & 63;
    if (tile < 32) wswz_tile(W1, w1hi, w1lo, 128, tile, lane);
    else           wswz_tile(W2, w2hi, w2lo, 64, tile - 32, lane);
  }
}

// ---------------- k_cg1: gemm1 (blocks < GB) || degree count (rest) -------
// gemm1: C[n,128] = A[n,128] @ W1, A fp32 split to bf16 hi/lo in regs,
// output bf16. count: 4 edges/thread, int4 loads, atomicAdd on cnt.
// Disjoint data between halves -> race-free fusion.
__global__ __launch_bounds__(256) void k_cg1(const float* __restrict__ Af32,
                                             const ushort* __restrict__ Whi,
                                             const ushort* __restrict__ Wlo,
                                             ushort* __restrict__ Cb, int n, int GB,
                                             const int* __restrict__ dst,
                                             int* __restrict__ cnt, int E) {
  constexpr int K = 128, M = 128, NT = M / 16;
  int bid = blockIdx.x;
  if (bid >= GB) {  // ---- degree count ----
    int e0 = (bid - GB) * 1024 + threadIdx.x * 4;
    if (e0 < E) {
      int4 d = *(const int4*)(dst + e0);
      atomicAdd(&cnt[d.x], 1);
      if (e0 + 1 < E) atomicAdd(&cnt[d.y], 1);
      if (e0 + 2 < E) atomicAdd(&cnt[d.z], 1);
      if (e0 + 3 < E) atomicAdd(&cnt[d.w], 1);
    }
    return;
  }
  // ---- gemm1 ----
  int lane = threadIdx.x & 63;
  int wv = threadIdx.x >> 6;
  int quad = lane >> 4, lo16 = lane & 15;
  int rowbase = bid * 64 + wv * 16;
  int arow = rowbase + lo16;
  bool arow_ok = arow < n;
  float4v acc[NT];
#pragma unroll
  for (int nt = 0; nt < NT; nt++) acc[nt] = (float4v){0.f, 0.f, 0.f, 0.f};
  for (int kt = 0; kt < 4; kt++) {
    short8 ahi, alo;
    float av[8];
    if (arow_ok) {
      const float* ap = Af32 + (size_t)arow * K + kt * 32 + quad * 8;
      float4 a0 = *(const float4*)ap;
      float4 a1 = *(const float4*)(ap + 4);
      av[0] = a0.x; av[1] = a0.y; av[2] = a0.z; av[3] = a0.w;
      av[4] = a1.x; av[5] = a1.y; av[6] = a1.z; av[7] = a1.w;
    } else {
#pragma unroll
      for (int j = 0; j < 8; j++) av[j] = 0.f;
    }
#pragma unroll
    for (int j = 0; j < 8; j++) {
      ushort h = f2bf(av[j]);
      ahi[j] = (short)h;
      alo[j] = (short)f2bf(av[j] - bf2f(h));
    }
    const ushort* ph = Whi + ((size_t)(kt * NT) * 64 + lane) * 8;
    const ushort* pl = Wlo + ((size_t)(kt * NT) * 64 + lane) * 8;
#pragma unroll
    for (int nt = 0; nt < NT; nt++) {
      short8 bhi = *(const short8*)(ph + nt * 512);
      short8 blo = *(const short8*)(pl + nt * 512);
      acc[nt] = __builtin_amdgcn_mfma_f32_16x16x32_bf16(ahi, bhi, acc[nt], 0, 0, 0);
      acc[nt] = __builtin_amdgcn_mfma_f32_16x16x32_bf16(alo, bhi, acc[nt], 0, 0, 0);
      acc[nt] = __builtin_amdgcn_mfma_f32_16x16x32_bf16(ahi, blo, acc[nt], 0, 0, 0);
    }
  }
  // D layout (m89-verified): col = lane&15, row = quad*4 + reg
#pragma unroll
  for (int nt = 0; nt < NT; nt++) {
#pragma unroll
    for (int r = 0; r < 4; r++) {
      int row = rowbase + quad * 4 + r;
      if (row < n) Cb[(size_t)row * M + nt * 16 + lo16] = f2bf(acc[nt][r]);
    }
  }
}

// ---------------- hierarchical scan (proven R2-R4 version) ----------------
__global__ __launch_bounds__(256) void k_scan1(const int* __restrict__ cnt,
                                               int* __restrict__ excl,
                                               int* __restrict__ bsum, int n) {
  __shared__ int buf[256];
  int t = threadIdx.x;
  int i = blockIdx.x * 256 + t;
  int v = (i < n) ? cnt[i] : 0;
  buf[t] = v;
  __syncthreads();
#pragma unroll
  for (int off = 1; off < 256; off <<= 1) {
    int add = (t >= off) ? buf[t - off] : 0;
    __syncthreads();
    buf[t] += add;
    __syncthreads();
  }
  if (i < n) excl[i] = buf[t] - v;
  if (t == 255) bsum[blockIdx.x] = buf[255];
}

__global__ __launch_bounds__(256) void k_scan2(int* __restrict__ bsum, int nb) {
  __shared__ int buf[256];
  int t = threadIdx.x;
  int v = (t < nb) ? bsum[t] : 0;
  buf[t] = v;
  __syncthreads();
#pragma unroll
  for (int off = 1; off < 256; off <<= 1) {
    int add = (t >= off) ? buf[t - off] : 0;
    __syncthreads();
    buf[t] += add;
    __syncthreads();
  }
  if (t < nb) bsum[t] = buf[t] - v;
}

__global__ __launch_bounds__(256) void k_scan3(const int* __restrict__ cnt,
                                               const int* __restrict__ excl,
                                               const int* __restrict__ bsum,
                                               int* __restrict__ row_ptr,
                                               int* __restrict__ cursor,
                                               float* __restrict__ dinv, int n, int E) {
  int i = blockIdx.x * 256 + threadIdx.x;
  if (i < n) {
    int e = excl[i] + bsum[i >> 8];
    row_ptr[i] = e;
    cursor[i]  = e;
    dinv[i]    = rsqrtf((float)(cnt[i] + 1));  // +1 self loop
  }
  if (i == 0) row_ptr[n] = E;
}

// 4 edges/thread, int4 loads
__global__ __launch_bounds__(256) void k_fill(const int* __restrict__ src,
                                              const int* __restrict__ dst,
                                              int* __restrict__ cursor,
                                              int* __restrict__ col, int E) {
  int e0 = blockIdx.x * 1024 + threadIdx.x * 4;
  if (e0 >= E) return;
  int4 s = *(const int4*)(src + e0);
  int4 d = *(const int4*)(dst + e0);
  col[atomicAdd(&cursor[d.x], 1)] = s.x;
  if (e0 + 1 < E) col[atomicAdd(&cursor[d.y], 1)] = s.y;
  if (e0 + 2 < E) col[atomicAdd(&cursor[d.z], 1)] = s.z;
  if (e0 + 3 < E) col[atomicAdd(&cursor[d.w], 1)] = s.w;
}

// ---------------- gemm2: PRESPLIT bf16 hi/lo in, bf16 out ----------------
__global__ __launch_bounds__(256) void k_gemm2(const ushort* __restrict__ Ahi,
                                               const ushort* __restrict__ Alo,
                                               const ushort* __restrict__ Whi,
                                               const ushort* __restrict__ Wlo,
                                               ushort* __restrict__ Cb, int n) {
  constexpr int K = 128, M = 64, NT = M / 16;
  int lane = threadIdx.x & 63;
  int wv = threadIdx.x >> 6;
  int quad = lane >> 4, lo16 = lane & 15;
  int rowbase = blockIdx.x * 64 + wv * 16;
  int arow = rowbase + lo16;
  bool arow_ok = arow < n;
  float4v acc[NT];
#pragma unroll
  for (int nt = 0; nt < NT; nt++) acc[nt] = (float4v){0.f, 0.f, 0.f, 0.f};
  for (int kt = 0; kt < 4; kt++) {
    short8 ahi, alo;
    if (arow_ok) {
      size_t ao = (size_t)arow * K + kt * 32 + quad * 8;
      ahi = *(const short8*)(Ahi + ao);
      alo = *(const short8*)(Alo + ao);
    } else {
      ahi = (short8)0; alo = (short8)0;
    }
    const ushort* ph = Whi + ((size_t)(kt * NT) * 64 + lane) * 8;
    const ushort* pl = Wlo + ((size_t)(kt * NT) * 64 + lane) * 8;
#pragma unroll
    for (int nt = 0; nt < NT; nt++) {
      short8 bhi = *(const short8*)(ph + nt * 512);
      short8 blo = *(const short8*)(pl + nt * 512);
      acc[nt] = __builtin_amdgcn_mfma_f32_16x16x32_bf16(ahi, bhi, acc[nt], 0, 0, 0);
      acc[nt] = __builtin_amdgcn_mfma_f32_16x16x32_bf16(alo, bhi, acc[nt], 0, 0, 0);
      acc[nt] = __builtin_amdgcn_mfma_f32_16x16x32_bf16(ahi, blo, acc[nt], 0, 0, 0);
    }
  }
#pragma unroll
  for (int nt = 0; nt < NT; nt++) {
#pragma unroll
    for (int r = 0; r < 4; r++) {
      int row = rowbase + quad * 4 + r;
      if (row < n) Cb[(size_t)row * M + nt * 16 + lo16] = f2bf(acc[nt][r]);
    }
  }
}

// ---------------- aggregation (unchanged from R4) -------------------------
template <int C, bool RELU, bool SPLIT>
__global__ __launch_bounds__(256) void k_agg(const ushort* __restrict__ Hb,
                                             const int* __restrict__ row_ptr,
                                             const int* __restrict__ col,
                                             const float* __restrict__ dinv,
                                             const float* __restrict__ bias,
                                             float* __restrict__ out,
                                             ushort* __restrict__ outhi,
                                             ushort* __restrict__ outlo, int n) {
  constexpr int VPL = C / 64;  // 2 (C=128) or 1 (C=64)
  int lane = threadIdx.x & 63;
  int v = blockIdx.x * 4 + (threadIdx.x >> 6);
  if (v >= n) return;
  float dv = dinv[v];
  float acc0 = 0.f, acc1 = 0.f;
  auto loadp = [&](int s) -> unsigned {
    if (VPL == 2) return *(const unsigned*)(Hb + (size_t)s * C + lane * 2);
    else          return (unsigned)Hb[(size_t)s * C + lane];
  };
  {
    unsigned u = loadp(v);  // self loop (weight dv)
    if (VPL == 2) { acc0 = dv * bflo(u); acc1 = dv * bfhi(u); }
    else          { acc0 = dv * bf2f((ushort)u); }
  }
  int beg = row_ptr[v], end = row_ptr[v + 1];
  for (int base = beg; base < end; base += 64) {
    int m = end - base;
    if (m > 64) m = 64;
    int sl = 0;
    float wl = 0.f;
    if (lane < m) {
      sl = col[base + lane];
      wl = dinv[sl];
    }
    int j = 0;
    for (; j + 8 <= m; j += 8) {
      int s[8]; float wq[8]; unsigned u[8];
#pragma unroll
      for (int q = 0; q < 8; q++) { s[q] = __shfl(sl, j + q); wq[q] = __shfl(wl, j + q); }
#pragma unroll
      for (int q = 0; q < 8; q++) u[q] = loadp(s[q]);
#pragma unroll
      for (int q = 0; q < 8; q++) {
        if (VPL == 2) {
          acc0 = fmaf(wq[q], bflo(u[q]), acc0);
          acc1 = fmaf(wq[q], bfhi(u[q]), acc1);
        } else {
          acc0 = fmaf(wq[q], bf2f((ushort)u[q]), acc0);
        }
      }
    }
    for (; j + 4 <= m; j += 4) {
      int s[4]; float wq[4]; unsigned u[4];
#pragma unroll
      for (int q = 0; q < 4; q++) { s[q] = __shfl(sl, j + q); wq[q] = __shfl(wl, j + q); }
#pragma unroll
      for (int q = 0; q < 4; q++) u[q] = loadp(s[q]);
#pragma unroll
      for (int q = 0; q < 4; q++) {
        if (VPL == 2) {
          acc0 = fmaf(wq[q], bflo(u[q]), acc0);
          acc1 = fmaf(wq[q], bfhi(u[q]), acc1);
        } else {
          acc0 = fmaf(wq[q], bf2f((ushort)u[q]), acc0);
        }
      }
    }
    for (; j < m; j++) {
      int s = __shfl(sl, j);
      float wv = __shfl(wl, j);
      unsigned u = loadp(s);
      if (VPL == 2) {
        acc0 = fmaf(wv, bflo(u), acc0);
        acc1 = fmaf(wv, bfhi(u), acc1);
      } else {
        acc0 = fmaf(wv, bf2f((ushort)u), acc0);
      }
    }
  }
  float r0 = fmaf(dv, acc0, bias[lane * VPL + 0]);
  if (RELU) r0 = fmaxf(r0, 0.f);
  if (VPL == 2) {
    float r1 = fmaf(dv, acc1, bias[lane * VPL + 1]);
    if (RELU) r1 = fmaxf(r1, 0.f);
    if (SPLIT) {
      ushort h0 = f2bf(r0), h1 = f2bf(r1);
      ushort l0 = f2bf(r0 - bf2f(h0)), l1 = f2bf(r1 - bf2f(h1));
      ((unsigned*)outhi)[(size_t)v * (C / 2) + lane] = (unsigned)h0 | ((unsigned)h1 << 16);
      ((unsigned*)outlo)[(size_t)v * (C / 2) + lane] = (unsigned)l0 | ((unsigned)l1 << 16);
    } else {
      *(float2*)&out[(size_t)v * C + lane * 2] = make_float2(r0, r1);
    }
  } else {
    if (SPLIT) {
      ushort h0 = f2bf(r0);
      outhi[(size_t)v * C + lane] = h0;
      outlo[(size_t)v * C + lane] = f2bf(r0 - bf2f(h0));
    } else {
      out[(size_t)v * C + lane] = r0;
    }
  }
}

extern "C" void kernel_launch(void* const* d_in, const int* in_sizes, int n_in,
                              void* d_out, int out_size, void* d_ws, size_t ws_size,
                              hipStream_t stream) {
  const float* x  = (const float*)d_in[0];
  const int*   ei = (const int*)d_in[1];
  const float* W1 = (const float*)d_in[2];
  const float* b1 = (const float*)d_in[3];
  const float* W2 = (const float*)d_in[4];
  const float* b2 = (const float*)d_in[5];
  int N = in_sizes[0] / 128;
  int E = in_sizes[1] / 2;
  const int* src = ei;
  const int* dst = ei + E;
  int nb = (N + 255) / 256;  // 196; must be <= 256 for k_scan2

  auto al = [](size_t v) { return (v + 255) & ~(size_t)255; };
  char* w = (char*)d_ws;
  int*      cnt     = (int*)w;      w += al((size_t)N * 4);
  float*    dinv    = (float*)w;    w += al((size_t)N * 4);
  int*      row_ptr = (int*)w;      w += al((size_t)(N + 1) * 4);
  int*      cursor  = (int*)w;      w += al((size_t)N * 4);
  int*      excl    = (int*)w;      w += al((size_t)N * 4);
  int*      bsum    = (int*)w;      w += al((size_t)nb * 4);
  int*      colv    = (int*)w;      w += al((size_t)E * 4);
  ushort*   h       = (ushort*)w;   w += al((size_t)N * 128 * 2);
  ushort*   h1hi    = (ushort*)w;   w += al((size_t)N * 128 * 2);
  ushort*   h1lo    = (ushort*)w;   w += al((size_t)N * 128 * 2);
  ushort*   h2      = (ushort*)w;   w += al((size_t)N * 64 * 2);
  ushort*   w1hi    = (ushort*)w;   w += al((size_t)128 * 128 * 2);
  ushort*   w1lo    = (ushort*)w;   w += al((size_t)128 * 128 * 2);
  ushort*   w2hi    = (ushort*)w;   w += al((size_t)128 * 64 * 2);
  ushort*   w2lo    = (ushort*)w;   w += al((size_t)128 * 64 * 2);
  float* out = (float*)d_out;

  int GB = (N + 63) / 64;               // 782 gemm blocks
  int CB = (E / 4 + 255) / 256;         // 586 count/fill blocks

  k_pre<<<nb + 12, 256, 0, stream>>>(cnt, N, nb, W1, w1hi, w1lo, W2, w2hi, w2lo);
  k_cg1<<<GB + CB, 256, 0, stream>>>(x, w1hi, w1lo, h, N, GB, dst, cnt, E);
  k_scan1<<<nb, 256, 0, stream>>>(cnt, excl, bsum, N);
  k_scan2<<<1, 256, 0, stream>>>(bsum, nb);
  k_scan3<<<nb, 256, 0, stream>>>(cnt, excl, bsum, row_ptr, cursor, dinv, N, E);
  k_fill<<<CB, 256, 0, stream>>>(src, dst, cursor, colv, E);
  k_agg<128, true, true><<<(N + 3) / 4, 256, 0, stream>>>(h, row_ptr, colv, dinv, b1,
                                                          nullptr, h1hi, h1lo, N);
  k_gemm2<<<GB, 256, 0, stream>>>(h1hi, h1lo, w2hi, w2lo, h2, N);
  k_agg<64, false, false><<<(N + 3) / 4, 256, 0, stream>>>(h2, row_ptr, colv, dinv, b2,
                                                           out, nullptr, nullptr, N);
}

// Round 7
// 175.520 us; speedup vs baseline: 2.1738x; 1.2426x over previous
//
#include <hip/hip_runtime.h>

// GCN encoder: 2x (dense transform -> symmetric-normalized neighbor aggregation)
// R3: bf16x3 split MFMA GEMMs (no fp32 MFMA on CDNA4), W pre-swizzled.
// R4: aggregation gather tables bf16 -> halved beyond-L2 gather traffic.
// R5 FAILED: cross-thread fence race in ticket scan -> OOB -> abort.
// R6: race-free fusions only; 218 us. Profile: k_cg1 43.7 us with ALL pipes
//     idle -> 600K random device atomics (count) = ~13.7 G atomics/s wall;
//     k_fill is the same wall hidden below top-5. CSR build ~= 90 us.
// R7: atomic-free CSR build via bucket partition (bucket = dst>>7, 128
//     nodes/bucket, NBK=391). All counters/cursors in LDS; cross-block
//     comms only via kernel boundaries. 7 dispatches total.
//     NOTE: assumes N <= 65536 (NBK <= 512 LDS arrays) and src/N < 2^25
//     for the packed partition format.

typedef __attribute__((ext_vector_type(8))) short short8;
typedef __attribute__((ext_vector_type(4))) float float4v;

constexpr int PB = 128;  // partition blocks

static __device__ __forceinline__ ushort f2bf(float f) {
  union { float f; unsigned u; } c; c.f = f;
  unsigned u = c.u;
  return (ushort)((u + 0x7fffu + ((u >> 16) & 1u)) >> 16);  // RNE
}
static __device__ __forceinline__ float bf2f(ushort h) {
  union { unsigned u; float f; } c; c.u = ((unsigned)h) << 16;
  return c.f;
}
static __device__ __forceinline__ float bfhi(unsigned packed) {
  union { unsigned u; float f; } c; c.u = packed & 0xffff0000u;
  return c.f;
}
static __device__ __forceinline__ float bflo(unsigned packed) {
  union { unsigned u; float f; } c; c.u = packed << 16;
  return c.f;
}

// W swizzle body: one 16x32 B-fragment tile (64 lanes).
// Layout [ktile][ntile][lane][j]: B[k=(lane>>4)*8+j][n=lane&15]
static __device__ __forceinline__ void wswz_tile(const float* __restrict__ W,
                                                 ushort* __restrict__ whi,
                                                 ushort* __restrict__ wlo,
                                                 int M, int tile, int lane) {
  int ntiles = M >> 4;
  int kt = tile / ntiles, nt = tile % ntiles;
  int colg = nt * 16 + (lane & 15);
  int krow = kt * 32 + (lane >> 4) * 8;
  size_t o = ((size_t)tile * 64 + lane) * 8;
#pragma unroll
  for (int j = 0; j < 8; j++) {
    float v = W[(size_t)(krow + j) * M + colg];
    ushort h = f2bf(v);
    whi[o + j] = h;
    wlo[o + j] = f2bf(v - bf2f(h));
  }
}

// Exclusive scan of m (<512) global ints into LDS base[512]; base[m] = total.
// All 256 threads participate (uniform control flow around __syncthreads).
static __device__ __forceinline__ void lds_scan512(const int* __restrict__ g, int m,
                                                   int* __restrict__ base,
                                                   int* __restrict__ buf) {
  int t = threadIdx.x;
  int carry = 0;
  for (int b0 = 0; b0 < 512; b0 += 256) {
    int idx = b0 + t;
    int v = (idx < m) ? g[idx] : 0;
    buf[t] = v;
    __syncthreads();
    for (int off = 1; off < 256; off <<= 1) {
      int add = (t >= off) ? buf[t - off] : 0;
      __syncthreads();
      buf[t] += add;
      __syncthreads();
    }
    base[idx] = carry + buf[t] - v;
    carry += buf[255];
    __syncthreads();
  }
}

// ---------------- P1: bucket histogram (LDS) + W swizzles -----------------
// blocks [0,PB): histogram chunk -> cnt_mat[bucket*PB + block]
// blocks [PB,PB+12): 4 swizzle tiles each (W1 tiles 0..31, W2 tiles 32..47)
__global__ __launch_bounds__(256) void k_p1(const int* __restrict__ dst, int E, int EPB,
                                            int NBK, int* __restrict__ cnt_mat,
                                            const float* __restrict__ W1,
                                            ushort* __restrict__ w1hi,
                                            ushort* __restrict__ w1lo,
                                            const float* __restrict__ W2,
                                            ushort* __restrict__ w2hi,
                                            ushort* __restrict__ w2lo) {
  __shared__ int hist[512];
  int b = blockIdx.x, t = threadIdx.x;
  if (b >= PB) {
    int tile = (b - PB) * 4 + (t >> 6);
    int lane = t & 63;
    if (tile < 32) wswz_tile(W1, w1hi, w1lo, 128, tile, lane);
    else           wswz_tile(W2, w2hi, w2lo, 64, tile - 32, lane);
    return;
  }
  for (int k = t; k < NBK; k += 256) hist[k] = 0;
  __syncthreads();
  int start = b * EPB;
  int stop = min(E, start + EPB);
  for (int e = start + t * 4; e < stop; e += 1024) {
    if (e + 4 <= stop) {
      int4 d = *(const int4*)(dst + e);
      atomicAdd(&hist[d.x >> 7], 1);
      atomicAdd(&hist[d.y >> 7], 1);
      atomicAdd(&hist[d.z >> 7], 1);
      atomicAdd(&hist[d.w >> 7], 1);
    } else {
      for (int j = e; j < stop; j++) atomicAdd(&hist[dst[j] >> 7], 1);
    }
  }
  __syncthreads();
  for (int k = t; k < NBK; k += 256) cnt_mat[k * PB + b] = hist[k];
}

// ---------------- P2: per-bucket block scan (in place) || gemm1 -----------
// blocks [0,NBK): scan cnt_mat row -> within-bucket exclusive offsets; btot.
// blocks [NBK, NBK+GB): gemm1 bf16x3 MFMA, fp32 A split in regs, bf16 out.
__global__ __launch_bounds__(256) void k_p2(int* __restrict__ cnt_mat,
                                            int* __restrict__ btot, int NBK,
                                            const float* __restrict__ Af32,
                                            const ushort* __restrict__ Whi,
                                            const ushort* __restrict__ Wlo,
                                            ushort* __restrict__ Cb, int n) {
  __shared__ int buf[256];
  int bid = blockIdx.x, t = threadIdx.x;
  if (bid < NBK) {
    int v = (t < PB) ? cnt_mat[bid * PB + t] : 0;
    buf[t] = v;
    __syncthreads();
#pragma unroll
    for (int off = 1; off < 256; off <<= 1) {
      int add = (t >= off) ? buf[t - off] : 0;
      __syncthreads();
      buf[t] += add;
      __syncthreads();
    }
    if (t < PB) cnt_mat[bid * PB + t] = buf[t] - v;
    if (t == 255) btot[bid] = buf[255];
    return;
  }
  // ---- gemm1 ----
  constexpr int K = 128, M = 128, NT = M / 16;
  int lane = t & 63;
  int wv = t >> 6;
  int quad = lane >> 4, lo16 = lane & 15;
  int rowbase = (bid - NBK) * 64 + wv * 16;
  int arow = rowbase + lo16;
  bool arow_ok = arow < n;
  float4v acc[NT];
#pragma unroll
  for (int nt = 0; nt < NT; nt++) acc[nt] = (float4v){0.f, 0.f, 0.f, 0.f};
  for (int kt = 0; kt < 4; kt++) {
    short8 ahi, alo;
    float av[8];
    if (arow_ok) {
      const float* ap = Af32 + (size_t)arow * K + kt * 32 + quad * 8;
      float4 a0 = *(const float4*)ap;
      float4 a1 = *(const float4*)(ap + 4);
      av[0] = a0.x; av[1] = a0.y; av[2] = a0.z; av[3] = a0.w;
      av[4] = a1.x; av[5] = a1.y; av[6] = a1.z; av[7] = a1.w;
    } else {
#pragma unroll
      for (int j = 0; j < 8; j++) av[j] = 0.f;
    }
#pragma unroll
    for (int j = 0; j < 8; j++) {
      ushort h = f2bf(av[j]);
      ahi[j] = (short)h;
      alo[j] = (short)f2bf(av[j] - bf2f(h));
    }
    const ushort* ph = Whi + ((size_t)(kt * NT) * 64 + lane) * 8;
    const ushort* pl = Wlo + ((size_t)(kt * NT) * 64 + lane) * 8;
#pragma unroll
    for (int nt = 0; nt < NT; nt++) {
      short8 bhi = *(const short8*)(ph + nt * 512);
      short8 blo = *(const short8*)(pl + nt * 512);
      acc[nt] = __builtin_amdgcn_mfma_f32_16x16x32_bf16(ahi, bhi, acc[nt], 0, 0, 0);
      acc[nt] = __builtin_amdgcn_mfma_f32_16x16x32_bf16(alo, bhi, acc[nt], 0, 0, 0);
      acc[nt] = __builtin_amdgcn_mfma_f32_16x16x32_bf16(ahi, blo, acc[nt], 0, 0, 0);
    }
  }
  // D layout (m89-verified): col = lane&15, row = quad*4 + reg
#pragma unroll
  for (int nt = 0; nt < NT; nt++) {
#pragma unroll
    for (int r = 0; r < 4; r++) {
      int row = rowbase + quad * 4 + r;
      if (row < n) Cb[(size_t)row * M + nt * 16 + lo16] = f2bf(acc[nt][r]);
    }
  }
}

// ---------------- P3: partition scatter (LDS cursors, disjoint ranges) ----
// part[pos] = src | (dst&127)<<25, grouped by bucket.
__global__ __launch_bounds__(256) void k_p3(const int* __restrict__ src,
                                            const int* __restrict__ dst, int E, int EPB,
                                            int NBK, const int* __restrict__ btot,
                                            const int* __restrict__ cnt_mat,
                                            unsigned* __restrict__ part) {
  __shared__ int buf[256];
  __shared__ int base[512];
  __shared__ int cur[512];
  int b = blockIdx.x, t = threadIdx.x;
  lds_scan512(btot, NBK, base, buf);
  for (int k = t; k < NBK; k += 256) cur[k] = base[k] + cnt_mat[k * PB + b];
  __syncthreads();
  int start = b * EPB, stop = min(E, start + EPB);
  for (int e = start + t * 4; e < stop; e += 1024) {
    if (e + 4 <= stop) {
      int4 s = *(const int4*)(src + e);
      int4 d = *(const int4*)(dst + e);
      int p;
      p = atomicAdd(&cur[d.x >> 7], 1); part[p] = (unsigned)s.x | ((unsigned)(d.x & 127) << 25);
      p = atomicAdd(&cur[d.y >> 7], 1); part[p] = (unsigned)s.y | ((unsigned)(d.y & 127) << 25);
      p = atomicAdd(&cur[d.z >> 7], 1); part[p] = (unsigned)s.z | ((unsigned)(d.z & 127) << 25);
      p = atomicAdd(&cur[d.w >> 7], 1); part[p] = (unsigned)s.w | ((unsigned)(d.w & 127) << 25);
    } else {
      for (int j = e; j < stop; j++) {
        int p2 = atomicAdd(&cur[dst[j] >> 7], 1);
        part[p2] = (unsigned)src[j] | ((unsigned)(dst[j] & 127) << 25);
      }
    }
  }
}

// ---------------- P4: per-bucket local CSR (LDS count/scan/place) ---------
__global__ __launch_bounds__(256) void k_p4(const int* __restrict__ btot, int NBK,
                                            const unsigned* __restrict__ part,
                                            int* __restrict__ row_ptr,
                                            float* __restrict__ dinv,
                                            int* __restrict__ col, int n, int E) {
  __shared__ int buf[256];
  __shared__ int base[512];
  __shared__ int cnt[128];
  __shared__ int cur[128];
  int b = blockIdx.x, t = threadIdx.x;
  lds_scan512(btot, NBK, base, buf);
  int beg = base[b], end = base[b + 1];
  if (t < 128) cnt[t] = 0;
  __syncthreads();
  for (int e = beg + t; e < end; e += 256) atomicAdd(&cnt[part[e] >> 25], 1);
  __syncthreads();
  int v = (t < 128) ? cnt[t] : 0;
  buf[t] = v;
  __syncthreads();
#pragma unroll
  for (int off = 1; off < 256; off <<= 1) {
    int add = (t >= off) ? buf[t - off] : 0;
    __syncthreads();
    buf[t] += add;
    __syncthreads();
  }
  if (t < 128) {
    int excl = buf[t] - v;
    cur[t] = beg + excl;
    int node = b * 128 + t;
    if (node < n) {
      row_ptr[node] = beg + excl;
      dinv[node] = rsqrtf((float)(v + 1));  // +1 self loop
    }
  }
  if (b == 0 && t == 0) row_ptr[n] = E;
  __syncthreads();
  for (int e = beg + t; e < end; e += 256) {
    unsigned p = part[e];
    int pos = atomicAdd(&cur[p >> 25], 1);
    col[pos] = (int)(p & 0x01FFFFFFu);
  }
}

// ---------------- gemm2: PRESPLIT bf16 hi/lo in, bf16 out ----------------
__global__ __launch_bounds__(256) void k_gemm2(const ushort* __restrict__ Ahi,
                                               const ushort* __restrict__ Alo,
                                               const ushort* __restrict__ Whi,
                                               const ushort* __restrict__ Wlo,
                                               ushort* __restrict__ Cb, int n) {
  constexpr int K = 128, M = 64, NT = M / 16;
  int lane = threadIdx.x & 63;
  int wv = threadIdx.x >> 6;
  int quad = lane >> 4, lo16 = lane & 15;
  int rowbase = blockIdx.x * 64 + wv * 16;
  int arow = rowbase + lo16;
  bool arow_ok = arow < n;
  float4v acc[NT];
#pragma unroll
  for (int nt = 0; nt < NT; nt++) acc[nt] = (float4v){0.f, 0.f, 0.f, 0.f};
  for (int kt = 0; kt < 4; kt++) {
    short8 ahi, alo;
    if (arow_ok) {
      size_t ao = (size_t)arow * K + kt * 32 + quad * 8;
      ahi = *(const short8*)(Ahi + ao);
      alo = *(const short8*)(Alo + ao);
    } else {
      ahi = (short8)0; alo = (short8)0;
    }
    const ushort* ph = Whi + ((size_t)(kt * NT) * 64 + lane) * 8;
    const ushort* pl = Wlo + ((size_t)(kt * NT) * 64 + lane) * 8;
#pragma unroll
    for (int nt = 0; nt < NT; nt++) {
      short8 bhi = *(const short8*)(ph + nt * 512);
      short8 blo = *(const short8*)(pl + nt * 512);
      acc[nt] = __builtin_amdgcn_mfma_f32_16x16x32_bf16(ahi, bhi, acc[nt], 0, 0, 0);
      acc[nt] = __builtin_amdgcn_mfma_f32_16x16x32_bf16(alo, bhi, acc[nt], 0, 0, 0);
      acc[nt] = __builtin_amdgcn_mfma_f32_16x16x32_bf16(ahi, blo, acc[nt], 0, 0, 0);
    }
  }
#pragma unroll
  for (int nt = 0; nt < NT; nt++) {
#pragma unroll
    for (int r = 0; r < 4; r++) {
      int row = rowbase + quad * 4 + r;
      if (row < n) Cb[(size_t)row * M + nt * 16 + lo16] = f2bf(acc[nt][r]);
    }
  }
}

// ---------------- aggregation (unchanged from R4) -------------------------
template <int C, bool RELU, bool SPLIT>
__global__ __launch_bounds__(256) void k_agg(const ushort* __restrict__ Hb,
                                             const int* __restrict__ row_ptr,
                                             const int* __restrict__ col,
                                             const float* __restrict__ dinv,
                                             const float* __restrict__ bias,
                                             float* __restrict__ out,
                                             ushort* __restrict__ outhi,
                                             ushort* __restrict__ outlo, int n) {
  constexpr int VPL = C / 64;  // 2 (C=128) or 1 (C=64)
  int lane = threadIdx.x & 63;
  int v = blockIdx.x * 4 + (threadIdx.x >> 6);
  if (v >= n) return;
  float dv = dinv[v];
  float acc0 = 0.f, acc1 = 0.f;
  auto loadp = [&](int s) -> unsigned {
    if (VPL == 2) return *(const unsigned*)(Hb + (size_t)s * C + lane * 2);
    else          return (unsigned)Hb[(size_t)s * C + lane];
  };
  {
    unsigned u = loadp(v);  // self loop (weight dv)
    if (VPL == 2) { acc0 = dv * bflo(u); acc1 = dv * bfhi(u); }
    else          { acc0 = dv * bf2f((ushort)u); }
  }
  int beg = row_ptr[v], end = row_ptr[v + 1];
  for (int base = beg; base < end; base += 64) {
    int m = end - base;
    if (m > 64) m = 64;
    int sl = 0;
    float wl = 0.f;
    if (lane < m) {
      sl = col[base + lane];
      wl = dinv[sl];
    }
    int j = 0;
    for (; j + 8 <= m; j += 8) {
      int s[8]; float wq[8]; unsigned u[8];
#pragma unroll
      for (int q = 0; q < 8; q++) { s[q] = __shfl(sl, j + q); wq[q] = __shfl(wl, j + q); }
#pragma unroll
      for (int q = 0; q < 8; q++) u[q] = loadp(s[q]);
#pragma unroll
      for (int q = 0; q < 8; q++) {
        if (VPL == 2) {
          acc0 = fmaf(wq[q], bflo(u[q]), acc0);
          acc1 = fmaf(wq[q], bfhi(u[q]), acc1);
        } else {
          acc0 = fmaf(wq[q], bf2f((ushort)u[q]), acc0);
        }
      }
    }
    for (; j + 4 <= m; j += 4) {
      int s[4]; float wq[4]; unsigned u[4];
#pragma unroll
      for (int q = 0; q < 4; q++) { s[q] = __shfl(sl, j + q); wq[q] = __shfl(wl, j + q); }
#pragma unroll
      for (int q = 0; q < 4; q++) u[q] = loadp(s[q]);
#pragma unroll
      for (int q = 0; q < 4; q++) {
        if (VPL == 2) {
          acc0 = fmaf(wq[q], bflo(u[q]), acc0);
          acc1 = fmaf(wq[q], bfhi(u[q]), acc1);
        } else {
          acc0 = fmaf(wq[q], bf2f((ushort)u[q]), acc0);
        }
      }
    }
    for (; j < m; j++) {
      int s = __shfl(sl, j);
      float wv = __shfl(wl, j);
      unsigned u = loadp(s);
      if (VPL == 2) {
        acc0 = fmaf(wv, bflo(u), acc0);
        acc1 = fmaf(wv, bfhi(u), acc1);
      } else {
        acc0 = fmaf(wv, bf2f((ushort)u), acc0);
      }
    }
  }
  float r0 = fmaf(dv, acc0, bias[lane * VPL + 0]);
  if (RELU) r0 = fmaxf(r0, 0.f);
  if (VPL == 2) {
    float r1 = fmaf(dv, acc1, bias[lane * VPL + 1]);
    if (RELU) r1 = fmaxf(r1, 0.f);
    if (SPLIT) {
      ushort h0 = f2bf(r0), h1 = f2bf(r1);
      ushort l0 = f2bf(r0 - bf2f(h0)), l1 = f2bf(r1 - bf2f(h1));
      ((unsigned*)outhi)[(size_t)v * (C / 2) + lane] = (unsigned)h0 | ((unsigned)h1 << 16);
      ((unsigned*)outlo)[(size_t)v * (C / 2) + lane] = (unsigned)l0 | ((unsigned)l1 << 16);
    } else {
      *(float2*)&out[(size_t)v * C + lane * 2] = make_float2(r0, r1);
    }
  } else {
    if (SPLIT) {
      ushort h0 = f2bf(r0);
      outhi[(size_t)v * C + lane] = h0;
      outlo[(size_t)v * C + lane] = f2bf(r0 - bf2f(h0));
    } else {
      out[(size_t)v * C + lane] = r0;
    }
  }
}

extern "C" void kernel_launch(void* const* d_in, const int* in_sizes, int n_in,
                              void* d_out, int out_size, void* d_ws, size_t ws_size,
                              hipStream_t stream) {
  const float* x  = (const float*)d_in[0];
  const int*   ei = (const int*)d_in[1];
  const float* W1 = (const float*)d_in[2];
  const float* b1 = (const float*)d_in[3];
  const float* W2 = (const float*)d_in[4];
  const float* b2 = (const float*)d_in[5];
  int N = in_sizes[0] / 128;
  int E = in_sizes[1] / 2;
  const int* src = ei;
  const int* dst = ei + E;
  int NBK = (N + 127) / 128;                 // 391; must be <= 512
  int EPB = ((E + PB - 1) / PB + 3) & ~3;    // edges per partition block, x4

  auto al = [](size_t v) { return (v + 255) & ~(size_t)255; };
  char* w = (char*)d_ws;
  int*      cnt_mat = (int*)w;      w += al((size_t)NBK * PB * 4);
  int*      btot    = (int*)w;      w += al((size_t)NBK * 4);
  unsigned* part    = (unsigned*)w; w += al((size_t)E * 4);
  int*      row_ptr = (int*)w;      w += al((size_t)(N + 1) * 4);
  float*    dinv    = (float*)w;    w += al((size_t)N * 4);
  int*      colv    = (int*)w;      w += al((size_t)E * 4);
  ushort*   h       = (ushort*)w;   w += al((size_t)N * 128 * 2);
  ushort*   h1hi    = (ushort*)w;   w += al((size_t)N * 128 * 2);
  ushort*   h1lo    = (ushort*)w;   w += al((size_t)N * 128 * 2);
  ushort*   h2      = (ushort*)w;   w += al((size_t)N * 64 * 2);
  ushort*   w1hi    = (ushort*)w;   w += al((size_t)128 * 128 * 2);
  ushort*   w1lo    = (ushort*)w;   w += al((size_t)128 * 128 * 2);
  ushort*   w2hi    = (ushort*)w;   w += al((size_t)128 * 64 * 2);
  ushort*   w2lo    = (ushort*)w;   w += al((size_t)128 * 64 * 2);
  float* out = (float*)d_out;

  int GB = (N + 63) / 64;  // 782 gemm blocks

  k_p1<<<PB + 12, 256, 0, stream>>>(dst, E, EPB, NBK, cnt_mat,
                                    W1, w1hi, w1lo, W2, w2hi, w2lo);
  k_p2<<<NBK + GB, 256, 0, stream>>>(cnt_mat, btot, NBK, x, w1hi, w1lo, h, N);
  k_p3<<<PB, 256, 0, stream>>>(src, dst, E, EPB, NBK, btot, cnt_mat, part);
  k_p4<<<NBK, 256, 0, stream>>>(btot, NBK, part, row_ptr, dinv, colv, N, E);
  k_agg<128, true, true><<<(N + 3) / 4, 256, 0, stream>>>(h, row_ptr, colv, dinv, b1,
                                                          nullptr, h1hi, h1lo, N);
  k_gemm2<<<GB, 256, 0, stream>>>(h1hi, h1lo, w2hi, w2lo, h2, N);
  k_agg<64, false, false><<<(N + 3) / 4, 256, 0, stream>>>(h2, row_ptr, colv, dinv, b2,
                                                           out, nullptr, nullptr, N);
}